// Round 6
// baseline (358.518 us; speedup 1.0000x reference)
//
#include <hip/hip_runtime.h>

#define DD   256
#define TT   1024
#define BT   8192
#define KK   8192
#define ZQ_SIZE 2097152

#define FLT_INF 3.402823466e38f

typedef __attribute__((ext_vector_type(8))) short short8;
typedef __attribute__((ext_vector_type(4))) float f32x4;

// ws layout (bytes)
#define ASP_B   0u           // Asplit: 8192 x 768 bf16 (h|m|l)  = 12582912 B
#define BSP_B   12582912u    // Bsplit: same
#define AN_B    25165824u    // An: 8192 f32
#define CN_B    25198592u    // Cn: 8192 f32
#define KEY_B   25231360u    // keys: 8192 u64
#define ACC_B   25296896u    // loss acc: 1 f32
#define CNT_B   25296900u    // completion counter: 1 u32

static __device__ __forceinline__ unsigned short f2bf(float x) {  // RNE fp32->bf16
    unsigned int u = __float_as_uint(x);
    return (unsigned short)((u + 0x7FFF + ((u >> 16) & 1)) >> 16);
}
static __device__ __forceinline__ float bf2f(unsigned short h) {
    return __uint_as_float(((unsigned int)h) << 16);
}
// exact 3-term split: x == h + m + l (each difference exact in fp32)
static __device__ __forceinline__ void split3(float x, unsigned short& h,
                                              unsigned short& m, unsigned short& l) {
    h = f2bf(x);
    float r1 = x - bf2f(h);
    m = f2bf(r1);
    l = f2bf(r1 - bf2f(m));
}

static __device__ __forceinline__ void gld16(const void* g, const void* l) {
    __builtin_amdgcn_global_load_lds(
        (const __attribute__((address_space(1))) unsigned int*)g,
        (__attribute__((address_space(3))) unsigned int*)l, 16, 0, 0);
}

// ---------------- kernel 1: fused prep ----------------
// blocks 0..127:     An (64 tokens/block, 64 active lanes) + keys/acc/counter init
// blocks 128..2175:  Bsplit + Cn
// blocks 2176..2303: Asplit (via LDS transpose)
__global__ __launch_bounds__(256) void vq_prep(const float* __restrict__ z,
                                               const float* __restrict__ cb,
                                               float* __restrict__ An,
                                               unsigned short* __restrict__ Asp,
                                               unsigned short* __restrict__ Bsp,
                                               float* __restrict__ Cn,
                                               unsigned long long* __restrict__ keys,
                                               float* __restrict__ lacc,
                                               unsigned int* __restrict__ counter) {
    __shared__ float T[64][257];
    int tid = threadIdx.x;
    if (blockIdx.x < 128) {
        if (tid >= 64) return;
        int g = blockIdx.x * 64 + tid;               // 0..8191 token
        int b = g >> 10, t = g & 1023;
        const float* zp = z + (size_t)b * (DD * TT) + t;
        float s = 0.f;
        #pragma unroll 16
        for (int d = 0; d < DD; ++d) {
            float v = zp[d * TT];
            float v2 = v * v;
            s = s + v2;                              // same order as before: bitwise stable
        }
        An[g] = s;
        keys[g] = ~0ull;
        if (g == 0) { *lacc = 0.f; *counter = 0u; }
    } else if (blockIdx.x < 128 + 2048) {
        // Bsplit: cb row-major -> [code][h(256)|m(256)|l(256)] bf16 ; Cn fused
        int g = (blockIdx.x - 128) * 256 + tid;      // 0..524287
        int code = g >> 6, d4 = (g & 63) * 4;
        float4 v = *(const float4*)&cb[(size_t)code * DD + d4];
        unsigned short h[4], m[4], l[4];
        split3(v.x, h[0], m[0], l[0]);
        split3(v.y, h[1], m[1], l[1]);
        split3(v.z, h[2], m[2], l[2]);
        split3(v.w, h[3], m[3], l[3]);
        unsigned short* row = Bsp + (size_t)code * 768 + d4;
        *(ushort4*)&row[0]   = make_ushort4(h[0], h[1], h[2], h[3]);
        *(ushort4*)&row[256] = make_ushort4(m[0], m[1], m[2], m[3]);
        *(ushort4*)&row[512] = make_ushort4(l[0], l[1], l[2], l[3]);
        float s = v.x * v.x + v.y * v.y + v.z * v.z + v.w * v.w;
        #pragma unroll
        for (int off = 32; off; off >>= 1) s += __shfl_down(s, off, 64);
        if ((tid & 63) == 0) Cn[code] = s;
    } else {
        // Asplit via LDS transpose: z[b,d,t] -> Asp[token][h|m|l]
        int blk = blockIdx.x - 2176;                 // 0..127
        int b = blk >> 4;
        int t0 = (blk & 15) * 64;
        #pragma unroll
        for (int it = 0; it < 16; ++it) {
            int d = it * 16 + (tid >> 4);
            int t4 = (tid & 15) * 4;
            float4 v = *(const float4*)&z[(size_t)b * (DD * TT) + (size_t)d * TT + t0 + t4];
            T[t4 + 0][d] = v.x; T[t4 + 1][d] = v.y; T[t4 + 2][d] = v.z; T[t4 + 3][d] = v.w;
        }
        __syncthreads();
        int r = tid >> 2, q = tid & 3;
        int token = b * 1024 + t0 + r;
        unsigned short* arow = Asp + (size_t)token * 768;
        #pragma unroll
        for (int dd = 0; dd < 16; ++dd) {
            int d = dd * 16 + q * 4;
            unsigned short h[4], m[4], l[4];
            #pragma unroll
            for (int c = 0; c < 4; ++c) split3(T[r][d + c], h[c], m[c], l[c]);
            *(ushort4*)&arow[d]       = make_ushort4(h[0], h[1], h[2], h[3]);
            *(ushort4*)&arow[256 + d] = make_ushort4(m[0], m[1], m[2], m[3]);
            *(ushort4*)&arow[512 + d] = make_ushort4(l[0], l[1], l[2], l[3]);
        }
    }
}

// ---------------- kernel 2: bf16x3 MFMA distance GEMM + fused argmin ----------------
// 256x256 block tile, 8 waves of 64x128 (4 m-rows x 2 n-cols), BK=64,
// double-buffered 2x64 KB LDS.  Accumulation order bitwise identical to R5.
// K = 6 chunk-pairs x 256: (h,h')(h,m')(m,h')(h,l')(l,h')(m,m')
// aSC = {0,0,1,0,2,1} packed 0x120100 ; bSC = {0,1,0,2,0,1} packed 0x102010
__global__ __launch_bounds__(512, 2) void vq_scores(const unsigned short* __restrict__ Asp,
                                                    const unsigned short* __restrict__ Bsp,
                                                    const float* __restrict__ An,
                                                    const float* __restrict__ Cn,
                                                    unsigned long long* __restrict__ keys) {
    // [buf][ A(256x64) | B(256x64) ] bf16, XOR slot swizzle p = s ^ (row&7)
    __shared__ __attribute__((aligned(16))) unsigned short lds[2][32768];

    // 8x8 block-group swizzle over the 32x32 tile grid
    int bid = blockIdx.x;
    int g = bid >> 6, sl = bid & 63;
    int mt = (g >> 2) * 8 + (sl >> 3);
    int nt = (g & 3) * 8 + (sl & 7);
    const int token0 = mt * 256, code0 = nt * 256;

    const int wid = threadIdx.x >> 6, lane = threadIdx.x & 63;
    const int m0w = (wid >> 1) * 64;      // 4 m-rows of 64
    const int n0w = (wid & 1) * 128;      // 2 n-cols of 128

    // staging: wave wid loads A rows [wid*32, wid*32+32) and same B rows
    const int srl = lane >> 3;                    // row-within-8
    const int gslot = (lane & 7) ^ srl;           // logical k-slot this lane fetches
    const size_t arow = (size_t)(token0 + wid * 32 + srl) * 768 + gslot * 8;
    const size_t brow = (size_t)(code0 + wid * 32 + srl) * 768 + gslot * 8;
    const int ldsrow = (wid * 32) * 64;

    f32x4 acc[4][8];
    #pragma unroll
    for (int i = 0; i < 4; ++i)
        #pragma unroll
        for (int j = 0; j < 8; ++j) acc[i][j] = (f32x4){0.f, 0.f, 0.f, 0.f};

    // prologue: stage chunk 0 into buf 0
    #pragma unroll
    for (int n = 0; n < 4; ++n) {
        gld16(Asp + arow + (size_t)(n * 8) * 768, &lds[0][ldsrow + n * 8 * 64]);
        gld16(Bsp + brow + (size_t)(n * 8) * 768, &lds[0][16384 + ldsrow + n * 8 * 64]);
    }

    for (int t = 0; t < 24; ++t) {
        __syncthreads();   // drains buf[t&1] loads (vmcnt0); prev readers done
        if (t < 23) {      // prefetch chunk t+1 into the other buffer
            int c = (t + 1) >> 2, kk = (t + 1) & 3;
            int ka = ((0x120100 >> (c * 4)) & 15) * 256 + kk * 64;
            int kb = ((0x102010 >> (c * 4)) & 15) * 256 + kk * 64;
            int p = (t + 1) & 1;
            #pragma unroll
            for (int n = 0; n < 4; ++n) {
                gld16(Asp + arow + (size_t)(n * 8) * 768 + ka,
                      &lds[p][ldsrow + n * 8 * 64]);
                gld16(Bsp + brow + (size_t)(n * 8) * 768 + kb,
                      &lds[p][16384 + ldsrow + n * 8 * 64]);
            }
        }
        const unsigned short* A = &lds[t & 1][0];
        const unsigned short* B = &lds[t & 1][16384];

        #pragma unroll
        for (int h = 0; h < 2; ++h) {
            short8 af[4], bf[8];
            const int s0 = h * 4 + (lane >> 4);   // logical slot of this frag
            #pragma unroll
            for (int i = 0; i < 4; ++i) {
                int row = m0w + i * 16 + (lane & 15);
                af[i] = *(const short8*)&A[row * 64 + ((s0 ^ (row & 7)) * 8)];
            }
            #pragma unroll
            for (int j = 0; j < 8; ++j) {
                int row = n0w + j * 16 + (lane & 15);
                bf[j] = *(const short8*)&B[row * 64 + ((s0 ^ (row & 7)) * 8)];
            }
            #pragma unroll
            for (int i = 0; i < 4; ++i)
                #pragma unroll
                for (int j = 0; j < 8; ++j)
                    acc[i][j] = __builtin_amdgcn_mfma_f32_16x16x32_bf16(
                        af[i], bf[j], acc[i][j], 0, 0, 0);
        }
    }

    // epilogue: dist = fl(fl(A - 2B) + C); argmin; C/D layout col=lane&15, row=quad*4+reg
    const int quad = lane >> 4, col = lane & 15;
    float cn[8]; int cidx[8];
    #pragma unroll
    for (int j = 0; j < 8; ++j) {
        cidx[j] = code0 + n0w + j * 16 + col;
        cn[j] = Cn[cidx[j]];
    }
    #pragma unroll
    for (int i = 0; i < 4; ++i) {
        #pragma unroll
        for (int r = 0; r < 4; ++r) {
            int token = token0 + m0w + i * 16 + quad * 4 + r;
            float Ai = An[token];
            float bv = FLT_INF; int bi = 0;
            #pragma unroll
            for (int j = 0; j < 8; ++j) {
                float d1 = fmaf(-2.f, acc[i][j][r], Ai);   // fl(A-2B): 2B exact
                float dist = d1 + cn[j];                    // fl(+C)
                if (dist < bv) { bv = dist; bi = cidx[j]; }
            }
            #pragma unroll
            for (int off = 8; off; off >>= 1) {
                float ov = __shfl_down(bv, off, 16);
                int   oi = __shfl_down(bi, off, 16);
                if (ov < bv || (ov == bv && oi < bi)) { bv = ov; bi = oi; }
            }
            if (col == 0) {
                unsigned long long key =
                    ((unsigned long long)__float_as_uint(bv) << 32) | (unsigned)bi;
                atomicMin(&keys[token], key);
            }
        }
    }
}

// ---------------- kernel 3: gather z_q + ST out + indices + loss (fused finalize) ----------------
__global__ __launch_bounds__(256) void vq_gather(const float* __restrict__ z,
                                                 const float* __restrict__ cb,
                                                 const unsigned long long* __restrict__ keys,
                                                 float* __restrict__ out,
                                                 float* __restrict__ out_idx,
                                                 float* __restrict__ loss_acc,
                                                 unsigned int* __restrict__ counter,
                                                 float* __restrict__ out_loss) {
    int e4 = blockIdx.x * 256 + threadIdx.x;     // float4 index, 524288 total
    int t4 = e4 & 255;
    int rest = e4 >> 8;
    int d = rest & 255;
    int b = rest >> 8;
    int gbase = b * 1024 + t4 * 4;

    const int* klo = (const int*)keys;           // low word of each u64 key = index
    int i0 = klo[(size_t)(gbase + 0) * 2];
    int i1 = klo[(size_t)(gbase + 1) * 2];
    int i2 = klo[(size_t)(gbase + 2) * 2];
    int i3 = klo[(size_t)(gbase + 3) * 2];
    if (d == 0) {
        out_idx[gbase + 0] = (float)i0;
        out_idx[gbase + 1] = (float)i1;
        out_idx[gbase + 2] = (float)i2;
        out_idx[gbase + 3] = (float)i3;
    }

    float4 zv = *(const float4*)&z[(size_t)e4 * 4];
    float q0 = cb[(size_t)i0 * DD + d];
    float q1 = cb[(size_t)i1 * DD + d];
    float q2 = cb[(size_t)i2 * DD + d];
    float q3 = cb[(size_t)i3 * DD + d];

    float d0 = q0 - zv.x, d1 = q1 - zv.y, d2 = q2 - zv.z, d3 = q3 - zv.w;
    float4 o;                                    // replicate z + (z_q - z) rounding
    o.x = zv.x + d0; o.y = zv.y + d1; o.z = zv.z + d2; o.w = zv.w + d3;
    *(float4*)&out[(size_t)e4 * 4] = o;

    float s = d0 * d0 + d1 * d1 + d2 * d2 + d3 * d3;
    #pragma unroll
    for (int off = 32; off; off >>= 1) s += __shfl_down(s, off, 64);
    __shared__ float wsum[4];
    if ((threadIdx.x & 63) == 0) wsum[threadIdx.x >> 6] = s;
    __syncthreads();
    if (threadIdx.x == 0) {
        atomicAdd(loss_acc, wsum[0] + wsum[1] + wsum[2] + wsum[3]);
        __threadfence();
        unsigned int n = atomicAdd(counter, 1u);
        if (n == 2047u) {                         // last block finalizes the loss
            float total = atomicAdd(loss_acc, 0.f);   // device-coherent read
            *out_loss = 1.25f * total / 2097152.f;
        }
    }
}

extern "C" void kernel_launch(void* const* d_in, const int* in_sizes, int n_in,
                              void* d_out, int out_size, void* d_ws, size_t ws_size,
                              hipStream_t stream) {
    const float* z  = (const float*)d_in[0];
    const float* cb = (const float*)d_in[1];
    float* out = (float*)d_out;
    char*  w   = (char*)d_ws;

    unsigned short* Asp = (unsigned short*)(w + ASP_B);
    unsigned short* Bsp = (unsigned short*)(w + BSP_B);
    float* An = (float*)(w + AN_B);
    float* Cn = (float*)(w + CN_B);
    unsigned long long* keys = (unsigned long long*)(w + KEY_B);
    float* lacc = (float*)(w + ACC_B);
    unsigned int* counter = (unsigned int*)(w + CNT_B);

    vq_prep   <<<128 + 2048 + 128, 256, 0, stream>>>(z, cb, An, Asp, Bsp, Cn, keys,
                                                     lacc, counter);
    vq_scores <<<1024, 512, 0, stream>>>(Asp, Bsp, An, Cn, keys);
    vq_gather <<<ZQ_SIZE / 1024, 256, 0, stream>>>(z, cb, keys, out, out + ZQ_SIZE,
                                                   lacc, counter, out + ZQ_SIZE + BT);
}

// Round 7
// 344.872 us; speedup vs baseline: 1.0396x; 1.0396x over previous
//
#include <hip/hip_runtime.h>

#define DD   256
#define TT   1024
#define BT   8192
#define KK   8192
#define ZQ_SIZE 2097152

#define FLT_INF 3.402823466e38f

typedef __attribute__((ext_vector_type(8))) short short8;
typedef __attribute__((ext_vector_type(4))) float f32x4;

// ws layout (bytes)
#define ASP_B   0u           // Asplit: 8192 x 768 bf16 (h|m|l)  = 12582912 B
#define BSP_B   12582912u    // Bsplit: same
#define AN_B    25165824u    // An: 8192 f32
#define CN_B    25198592u    // Cn: 8192 f32
#define KEY_B   25231360u    // keys: 8192 u64
#define ACC_B   25296896u    // loss acc: 1 f32

static __device__ __forceinline__ unsigned short f2bf(float x) {  // RNE fp32->bf16
    unsigned int u = __float_as_uint(x);
    return (unsigned short)((u + 0x7FFF + ((u >> 16) & 1)) >> 16);
}
static __device__ __forceinline__ float bf2f(unsigned short h) {
    return __uint_as_float(((unsigned int)h) << 16);
}
// exact 3-term split: x == h + m + l (each difference exact in fp32)
static __device__ __forceinline__ void split3(float x, unsigned short& h,
                                              unsigned short& m, unsigned short& l) {
    h = f2bf(x);
    float r1 = x - bf2f(h);
    m = f2bf(r1);
    l = f2bf(r1 - bf2f(m));
}

static __device__ __forceinline__ void gld16(const void* g, const void* l) {
    __builtin_amdgcn_global_load_lds(
        (const __attribute__((address_space(1))) unsigned int*)g,
        (__attribute__((address_space(3))) unsigned int*)l, 16, 0, 0);
}

// ---------------- kernel 1: fused prep (R5 version) ----------------
// blocks 0..31:      An (token norms) + keys init + lacc init
// blocks 32..2079:   Bsplit + Cn
// blocks 2080..2207: Asplit (via LDS transpose)
__global__ __launch_bounds__(256) void vq_prep(const float* __restrict__ z,
                                               const float* __restrict__ cb,
                                               float* __restrict__ An,
                                               unsigned short* __restrict__ Asp,
                                               unsigned short* __restrict__ Bsp,
                                               float* __restrict__ Cn,
                                               unsigned long long* __restrict__ keys,
                                               float* __restrict__ lacc) {
    __shared__ float T[64][257];
    int tid = threadIdx.x;
    if (blockIdx.x < 32) {
        int g = blockIdx.x * 256 + tid;              // 0..8191 token
        int b = g >> 10, t = g & 1023;
        const float* zp = z + (size_t)b * (DD * TT) + t;
        float s = 0.f;
        #pragma unroll 8
        for (int d = 0; d < DD; ++d) {
            float v = zp[d * TT];
            float v2 = v * v;
            s = s + v2;
        }
        An[g] = s;
        keys[g] = ~0ull;
        if (g == 0) *lacc = 0.f;
    } else if (blockIdx.x < 32 + 2048) {
        // Bsplit: cb row-major -> [code][h(256)|m(256)|l(256)] bf16 ; Cn fused
        int g = (blockIdx.x - 32) * 256 + tid;       // 0..524287
        int code = g >> 6, d4 = (g & 63) * 4;
        float4 v = *(const float4*)&cb[(size_t)code * DD + d4];
        unsigned short h[4], m[4], l[4];
        split3(v.x, h[0], m[0], l[0]);
        split3(v.y, h[1], m[1], l[1]);
        split3(v.z, h[2], m[2], l[2]);
        split3(v.w, h[3], m[3], l[3]);
        unsigned short* row = Bsp + (size_t)code * 768 + d4;
        *(ushort4*)&row[0]   = make_ushort4(h[0], h[1], h[2], h[3]);
        *(ushort4*)&row[256] = make_ushort4(m[0], m[1], m[2], m[3]);
        *(ushort4*)&row[512] = make_ushort4(l[0], l[1], l[2], l[3]);
        float s = v.x * v.x + v.y * v.y + v.z * v.z + v.w * v.w;
        #pragma unroll
        for (int off = 32; off; off >>= 1) s += __shfl_down(s, off, 64);
        if ((tid & 63) == 0) Cn[code] = s;
    } else {
        // Asplit via LDS transpose: z[b,d,t] -> Asp[token][h|m|l]
        int blk = blockIdx.x - 2080;                 // 0..127
        int b = blk >> 4;
        int t0 = (blk & 15) * 64;
        #pragma unroll
        for (int it = 0; it < 16; ++it) {
            int d = it * 16 + (tid >> 4);
            int t4 = (tid & 15) * 4;
            float4 v = *(const float4*)&z[(size_t)b * (DD * TT) + (size_t)d * TT + t0 + t4];
            T[t4 + 0][d] = v.x; T[t4 + 1][d] = v.y; T[t4 + 2][d] = v.z; T[t4 + 3][d] = v.w;
        }
        __syncthreads();
        int r = tid >> 2, q = tid & 3;
        int token = b * 1024 + t0 + r;
        unsigned short* arow = Asp + (size_t)token * 768;
        #pragma unroll
        for (int dd = 0; dd < 16; ++dd) {
            int d = dd * 16 + q * 4;
            unsigned short h[4], m[4], l[4];
            #pragma unroll
            for (int c = 0; c < 4; ++c) split3(T[r][d + c], h[c], m[c], l[c]);
            *(ushort4*)&arow[d]       = make_ushort4(h[0], h[1], h[2], h[3]);
            *(ushort4*)&arow[256 + d] = make_ushort4(m[0], m[1], m[2], m[3]);
            *(ushort4*)&arow[512 + d] = make_ushort4(l[0], l[1], l[2], l[3]);
        }
    }
}

// ---------------- kernel 2: bf16x3 MFMA distance GEMM + fused argmin ----------------
// 128x256 block tile, 4 waves of 64x128 (2x2), BK=32, double-buffered 2x24 KB LDS
// -> 2 blocks/CU (cross-block barrier hiding).  Accumulation bitwise identical to R6:
// same MFMA instruction sequence per accumulator (sequential k within each pair).
// K = 6 chunk-pairs x 256: (h,h')(h,m')(m,h')(h,l')(l,h')(m,m')
// aSC = {0,0,1,0,2,1} packed 0x120100 ; bSC = {0,1,0,2,0,1} packed 0x102010
__global__ __launch_bounds__(256, 2) void vq_scores(const unsigned short* __restrict__ Asp,
                                                    const unsigned short* __restrict__ Bsp,
                                                    const float* __restrict__ An,
                                                    const float* __restrict__ Cn,
                                                    unsigned long long* __restrict__ keys) {
    // per buffer: A(128x32) 4096 shorts | B(256x32) 8192 shorts ; XOR slot swizzle
    __shared__ __attribute__((aligned(16))) unsigned short lds[2][12288];

    // block swizzle over 64(mt) x 32(nt) tile grid, 8x8 groups for L2 locality
    int bid = blockIdx.x;
    int g = bid >> 6, sl = bid & 63;
    int mt = (g >> 2) * 8 + (sl >> 3);    // 0..63
    int nt = (g & 3) * 8 + (sl & 7);      // 0..31
    const int token0 = mt * 128, code0 = nt * 256;

    const int wid = threadIdx.x >> 6, lane = threadIdx.x & 63;
    const int m0w = (wid >> 1) * 64;      // 2 m-rows of 64
    const int n0w = (wid & 1) * 128;      // 2 n-cols of 128

    // staging: wave wid loads A rows [wid*32,+32) (2 insts) and B rows [wid*64,+64) (4 insts)
    const int srl = lane >> 2;                    // 0..15 row-within-16
    const int gslot = (lane & 3) ^ (srl & 3);     // logical 16B k-slot this lane fetches
    const size_t arow = (size_t)(token0 + wid * 32 + srl) * 768 + gslot * 8;
    const size_t brow = (size_t)(code0 + wid * 64 + srl) * 768 + gslot * 8;
    const int albase = (wid * 32) * 32;           // shorts
    const int blbase = 4096 + (wid * 64) * 32;

    f32x4 acc[4][8];
    #pragma unroll
    for (int i = 0; i < 4; ++i)
        #pragma unroll
        for (int j = 0; j < 8; ++j) acc[i][j] = (f32x4){0.f, 0.f, 0.f, 0.f};

    // prologue: stage chunk 0 into buf 0
    #pragma unroll
    for (int n = 0; n < 2; ++n)
        gld16(Asp + arow + (size_t)(n * 16) * 768, &lds[0][albase + n * 16 * 32]);
    #pragma unroll
    for (int n = 0; n < 4; ++n)
        gld16(Bsp + brow + (size_t)(n * 16) * 768, &lds[0][blbase + n * 16 * 32]);

    const int quad = lane >> 4, col = lane & 15;

    for (int t = 0; t < 48; ++t) {
        __syncthreads();   // drains buf[t&1] loads (vmcnt0); prev readers done
        if (t < 47) {      // prefetch chunk t+1 into the other buffer
            int c = (t + 1) >> 3, kk = (t + 1) & 7;
            int ka = ((0x120100 >> (c * 4)) & 15) * 256 + kk * 32;
            int kb = ((0x102010 >> (c * 4)) & 15) * 256 + kk * 32;
            int p = (t + 1) & 1;
            #pragma unroll
            for (int n = 0; n < 2; ++n)
                gld16(Asp + arow + (size_t)(n * 16) * 768 + ka,
                      &lds[p][albase + n * 16 * 32]);
            #pragma unroll
            for (int n = 0; n < 4; ++n)
                gld16(Bsp + brow + (size_t)(n * 16) * 768 + kb,
                      &lds[p][blbase + n * 16 * 32]);
        }
        const unsigned short* A = &lds[t & 1][0];
        const unsigned short* B = &lds[t & 1][4096];

        short8 af[4], bf[8];
        #pragma unroll
        for (int i = 0; i < 4; ++i) {
            int row = m0w + i * 16 + col;
            af[i] = *(const short8*)&A[row * 32 + ((quad ^ (row & 3)) * 8)];
        }
        #pragma unroll
        for (int j = 0; j < 8; ++j) {
            int row = n0w + j * 16 + col;
            bf[j] = *(const short8*)&B[row * 32 + ((quad ^ (row & 3)) * 8)];
        }
        #pragma unroll
        for (int i = 0; i < 4; ++i)
            #pragma unroll
            for (int j = 0; j < 8; ++j)
                acc[i][j] = __builtin_amdgcn_mfma_f32_16x16x32_bf16(
                    af[i], bf[j], acc[i][j], 0, 0, 0);
    }

    // epilogue: dist = fl(fl(A - 2B) + C); argmin; C/D layout col=lane&15, row=quad*4+reg
    float cn[8]; int cidx[8];
    #pragma unroll
    for (int j = 0; j < 8; ++j) {
        cidx[j] = code0 + n0w + j * 16 + col;
        cn[j] = Cn[cidx[j]];
    }
    #pragma unroll
    for (int i = 0; i < 4; ++i) {
        #pragma unroll
        for (int r = 0; r < 4; ++r) {
            int token = token0 + m0w + i * 16 + quad * 4 + r;
            float Ai = An[token];
            float bv = FLT_INF; int bi = 0;
            #pragma unroll
            for (int j = 0; j < 8; ++j) {
                float d1 = fmaf(-2.f, acc[i][j][r], Ai);   // fl(A-2B): 2B exact
                float dist = d1 + cn[j];                    // fl(+C)
                if (dist < bv) { bv = dist; bi = cidx[j]; }
            }
            #pragma unroll
            for (int off = 8; off; off >>= 1) {
                float ov = __shfl_down(bv, off, 16);
                int   oi = __shfl_down(bi, off, 16);
                if (ov < bv || (ov == bv && oi < bi)) { bv = ov; bi = oi; }
            }
            if (col == 0) {
                unsigned long long key =
                    ((unsigned long long)__float_as_uint(bv) << 32) | (unsigned)bi;
                atomicMin(&keys[token], key);
            }
        }
    }
}

// ---------------- kernel 3: gather z_q + ST out + indices + loss partial (R5 version) ----------------
__global__ __launch_bounds__(256) void vq_gather(const float* __restrict__ z,
                                                 const float* __restrict__ cb,
                                                 const unsigned long long* __restrict__ keys,
                                                 float* __restrict__ out,
                                                 float* __restrict__ out_idx,
                                                 float* __restrict__ loss_acc) {
    int e4 = blockIdx.x * 256 + threadIdx.x;     // float4 index, 524288 total
    int t4 = e4 & 255;
    int rest = e4 >> 8;
    int d = rest & 255;
    int b = rest >> 8;
    int gbase = b * 1024 + t4 * 4;

    const int* klo = (const int*)keys;           // low word of each u64 key = index
    int i0 = klo[(size_t)(gbase + 0) * 2];
    int i1 = klo[(size_t)(gbase + 1) * 2];
    int i2 = klo[(size_t)(gbase + 2) * 2];
    int i3 = klo[(size_t)(gbase + 3) * 2];
    if (d == 0) {
        out_idx[gbase + 0] = (float)i0;
        out_idx[gbase + 1] = (float)i1;
        out_idx[gbase + 2] = (float)i2;
        out_idx[gbase + 3] = (float)i3;
    }

    float4 zv = *(const float4*)&z[(size_t)e4 * 4];
    float q0 = cb[(size_t)i0 * DD + d];
    float q1 = cb[(size_t)i1 * DD + d];
    float q2 = cb[(size_t)i2 * DD + d];
    float q3 = cb[(size_t)i3 * DD + d];

    float d0 = q0 - zv.x, d1 = q1 - zv.y, d2 = q2 - zv.z, d3 = q3 - zv.w;
    float4 o;                                    // replicate z + (z_q - z) rounding
    o.x = zv.x + d0; o.y = zv.y + d1; o.z = zv.z + d2; o.w = zv.w + d3;
    *(float4*)&out[(size_t)e4 * 4] = o;

    float s = d0 * d0 + d1 * d1 + d2 * d2 + d3 * d3;
    #pragma unroll
    for (int off = 32; off; off >>= 1) s += __shfl_down(s, off, 64);
    __shared__ float wsum[4];
    if ((threadIdx.x & 63) == 0) wsum[threadIdx.x >> 6] = s;
    __syncthreads();
    if (threadIdx.x == 0)
        atomicAdd(loss_acc, wsum[0] + wsum[1] + wsum[2] + wsum[3]);
}

// ---------------- kernel 4: finalize loss ----------------
__global__ void vq_loss(const float* __restrict__ loss_acc, float* __restrict__ out_loss) {
    *out_loss = 1.25f * (*loss_acc) / 2097152.f;
}

extern "C" void kernel_launch(void* const* d_in, const int* in_sizes, int n_in,
                              void* d_out, int out_size, void* d_ws, size_t ws_size,
                              hipStream_t stream) {
    const float* z  = (const float*)d_in[0];
    const float* cb = (const float*)d_in[1];
    float* out = (float*)d_out;
    char*  w   = (char*)d_ws;

    unsigned short* Asp = (unsigned short*)(w + ASP_B);
    unsigned short* Bsp = (unsigned short*)(w + BSP_B);
    float* An = (float*)(w + AN_B);
    float* Cn = (float*)(w + CN_B);
    unsigned long long* keys = (unsigned long long*)(w + KEY_B);
    float* lacc = (float*)(w + ACC_B);

    vq_prep   <<<32 + 2048 + 128, 256, 0, stream>>>(z, cb, An, Asp, Bsp, Cn, keys, lacc);
    vq_scores <<<2048, 256, 0, stream>>>(Asp, Bsp, An, Cn, keys);
    vq_gather <<<ZQ_SIZE / 1024, 256, 0, stream>>>(z, cb, keys, out, out + ZQ_SIZE, lacc);
    vq_loss   <<<1, 1, 0, stream>>>(lacc, out + ZQ_SIZE + BT);
}

// Round 8
// 298.545 us; speedup vs baseline: 1.2009x; 1.1552x over previous
//
#include <hip/hip_runtime.h>

#define DD   256
#define TT   1024
#define BT   8192
#define KK   8192
#define ZQ_SIZE 2097152

#define FLT_INF 3.402823466e38f

typedef __attribute__((ext_vector_type(8))) short short8;
typedef __attribute__((ext_vector_type(4))) float f32x4;

// ws layout (bytes)
#define ASP_B   0u           // Asplit: 8192 x 768 bf16 (h|m|l)  = 12582912 B
#define BSP_B   12582912u    // Bsplit: same
#define AN_B    25165824u    // An: 8192 f32
#define CN_B    25198592u    // Cn: 8192 f32
#define KEY_B   25231360u    // keys: 8192 u64
#define ACC_B   25296896u    // loss acc: 1 f32

static __device__ __forceinline__ unsigned short f2bf(float x) {  // RNE fp32->bf16
    unsigned int u = __float_as_uint(x);
    return (unsigned short)((u + 0x7FFF + ((u >> 16) & 1)) >> 16);
}
static __device__ __forceinline__ float bf2f(unsigned short h) {
    return __uint_as_float(((unsigned int)h) << 16);
}
// exact 3-term split: x == h + m + l (each difference exact in fp32)
static __device__ __forceinline__ void split3(float x, unsigned short& h,
                                              unsigned short& m, unsigned short& l) {
    h = f2bf(x);
    float r1 = x - bf2f(h);
    m = f2bf(r1);
    l = f2bf(r1 - bf2f(m));
}

static __device__ __forceinline__ void gld16(const void* g, const void* l) {
    __builtin_amdgcn_global_load_lds(
        (const __attribute__((address_space(1))) unsigned int*)g,
        (__attribute__((address_space(3))) unsigned int*)l, 16, 0, 0);
}

// ---------------- kernel 1: fused prep ----------------
// blocks 0..31:      An (token norms) + keys init + lacc init
// blocks 32..2079:   Bsplit + Cn
// blocks 2080..2207: Asplit (via LDS transpose)
__global__ __launch_bounds__(256) void vq_prep(const float* __restrict__ z,
                                               const float* __restrict__ cb,
                                               float* __restrict__ An,
                                               unsigned short* __restrict__ Asp,
                                               unsigned short* __restrict__ Bsp,
                                               float* __restrict__ Cn,
                                               unsigned long long* __restrict__ keys,
                                               float* __restrict__ lacc) {
    __shared__ float T[64][257];
    int tid = threadIdx.x;
    if (blockIdx.x < 32) {
        int g = blockIdx.x * 256 + tid;              // 0..8191 token
        int b = g >> 10, t = g & 1023;
        const float* zp = z + (size_t)b * (DD * TT) + t;
        float s = 0.f;
        #pragma unroll 8
        for (int d = 0; d < DD; ++d) {
            float v = zp[d * TT];
            float v2 = v * v;
            s = s + v2;
        }
        An[g] = s;
        keys[g] = ~0ull;
        if (g == 0) *lacc = 0.f;
    } else if (blockIdx.x < 32 + 2048) {
        // Bsplit: cb row-major -> [code][h(256)|m(256)|l(256)] bf16 ; Cn fused
        int g = (blockIdx.x - 32) * 256 + tid;       // 0..524287
        int code = g >> 6, d4 = (g & 63) * 4;
        float4 v = *(const float4*)&cb[(size_t)code * DD + d4];
        unsigned short h[4], m[4], l[4];
        split3(v.x, h[0], m[0], l[0]);
        split3(v.y, h[1], m[1], l[1]);
        split3(v.z, h[2], m[2], l[2]);
        split3(v.w, h[3], m[3], l[3]);
        unsigned short* row = Bsp + (size_t)code * 768 + d4;
        *(ushort4*)&row[0]   = make_ushort4(h[0], h[1], h[2], h[3]);
        *(ushort4*)&row[256] = make_ushort4(m[0], m[1], m[2], m[3]);
        *(ushort4*)&row[512] = make_ushort4(l[0], l[1], l[2], l[3]);
        float s = v.x * v.x + v.y * v.y + v.z * v.z + v.w * v.w;
        #pragma unroll
        for (int off = 32; off; off >>= 1) s += __shfl_down(s, off, 64);
        if ((tid & 63) == 0) Cn[code] = s;
    } else {
        // Asplit via LDS transpose: z[b,d,t] -> Asp[token][h|m|l]
        int blk = blockIdx.x - 2080;                 // 0..127
        int b = blk >> 4;
        int t0 = (blk & 15) * 64;
        #pragma unroll
        for (int it = 0; it < 16; ++it) {
            int d = it * 16 + (tid >> 4);
            int t4 = (tid & 15) * 4;
            float4 v = *(const float4*)&z[(size_t)b * (DD * TT) + (size_t)d * TT + t0 + t4];
            T[t4 + 0][d] = v.x; T[t4 + 1][d] = v.y; T[t4 + 2][d] = v.z; T[t4 + 3][d] = v.w;
        }
        __syncthreads();
        int r = tid >> 2, q = tid & 3;
        int token = b * 1024 + t0 + r;
        unsigned short* arow = Asp + (size_t)token * 768;
        #pragma unroll
        for (int dd = 0; dd < 16; ++dd) {
            int d = dd * 16 + q * 4;
            unsigned short h[4], m[4], l[4];
            #pragma unroll
            for (int c = 0; c < 4; ++c) split3(T[r][d + c], h[c], m[c], l[c]);
            *(ushort4*)&arow[d]       = make_ushort4(h[0], h[1], h[2], h[3]);
            *(ushort4*)&arow[256 + d] = make_ushort4(m[0], m[1], m[2], m[3]);
            *(ushort4*)&arow[512 + d] = make_ushort4(l[0], l[1], l[2], l[3]);
        }
    }
}

// ---------------- kernel 2: bf16x3 MFMA distance GEMM + fused argmin ----------------
// 256(M)x128(N) block tile, 4 waves of 64x128 stacked in M. BK=32 k-slices.
// Per k-slice: B parts {h',m',l'} resident (dbuf), A parts streamed h->m->l (dbuf),
// computing (h.h')(h.m')(h.l')(m.h')(m.m')(l.h') -- every part staged exactly once.
// Swizzle: physical slot q at row r holds logical slot ((q+(r>>2))&3)^(r&3)
// -> uniform 2-per-bank frag reads (conflict-free), contiguous gld16 stores.
__global__ __launch_bounds__(256, 2) void vq_scores(const unsigned short* __restrict__ Asp,
                                                    const unsigned short* __restrict__ Bsp,
                                                    const float* __restrict__ An,
                                                    const float* __restrict__ Cn,
                                                    unsigned long long* __restrict__ keys) {
    __shared__ __attribute__((aligned(16))) unsigned short Abuf[2][8192];   // 256r x 32k
    __shared__ __attribute__((aligned(16))) unsigned short Bbuf[2][12288];  // 3p x 128r x 32k

    // 8x8 block-group swizzle over the 32(mt) x 64(nt) tile grid
    int bid = blockIdx.x;
    int g = bid >> 6, sl = bid & 63;
    int mt = (g >> 3) * 8 + (sl >> 3);    // 0..31
    int nt = (g & 7) * 8 + (sl & 7);      // 0..63
    const int token0 = mt * 256, code0 = nt * 128;

    const int wid = threadIdx.x >> 6, lane = threadIdx.x & 63;
    const int m0w = wid * 64;             // 4 waves stacked in M; all share N=128

    // staging geometry: each gld16 covers 16 rows (64 lanes x 16B, 64B rows)
    const int srl = lane >> 2;                                // row-within-16
    const int sq  = lane & 3;                                 // physical slot
    const int fs  = (((sq + (srl >> 2)) & 3) ^ (srl & 3));    // logical slot fetched
    const size_t arow = (size_t)(token0 + wid * 64 + srl) * 768 + fs * 8;
    const size_t brow = (size_t)(code0 + srl) * 768 + fs * 8;
    const int albase = (wid * 64) * 32;                       // shorts

    f32x4 acc[4][8];
    #pragma unroll
    for (int i = 0; i < 4; ++i)
        #pragma unroll
        for (int j = 0; j < 8; ++j) acc[i][j] = (f32x4){0.f, 0.f, 0.f, 0.f};

    // prologue: stage B[kk=0] (all 3 parts) -> Bbuf[0], A-h[kk=0] -> Abuf[0]
    #pragma unroll
    for (int n = 0; n < 6; ++n) {
        int grp = wid * 6 + n;                    // 0..23
        int part = grp >> 3, rb = (grp & 7) * 16;
        gld16(Bsp + brow + (size_t)rb * 768 + part * 256,
              &Bbuf[0][part * 4096 + rb * 32]);
    }
    #pragma unroll
    for (int n = 0; n < 4; ++n)
        gld16(Asp + arow + (size_t)(n * 16) * 768, &Abuf[0][albase + n * 16 * 32]);

    const int quad = lane >> 4, col = lane & 15;
    const int qp = ((quad ^ (col & 3)) - (col >> 2)) & 3;     // physical slot for reads

    for (int kk = 0; kk < 8; ++kk) {
        #pragma unroll
        for (int ph = 0; ph < 3; ++ph) {
            __syncthreads();   // drains previous phase's gld16; prev readers done
            if (ph == 0) {        // stage A-m[kk] -> Abuf[(kk+1)&1]
                #pragma unroll
                for (int n = 0; n < 4; ++n)
                    gld16(Asp + arow + (size_t)(n * 16) * 768 + 256 + kk * 32,
                          &Abuf[(kk + 1) & 1][albase + n * 16 * 32]);
            } else if (ph == 1) { // stage A-l[kk] -> Abuf[kk&1]
                #pragma unroll
                for (int n = 0; n < 4; ++n)
                    gld16(Asp + arow + (size_t)(n * 16) * 768 + 512 + kk * 32,
                          &Abuf[kk & 1][albase + n * 16 * 32]);
            } else if (kk < 7) {  // stage B[kk+1] + A-h[kk+1] -> buf (kk+1)&1
                #pragma unroll
                for (int n = 0; n < 6; ++n) {
                    int grp = wid * 6 + n;
                    int part = grp >> 3, rb = (grp & 7) * 16;
                    gld16(Bsp + brow + (size_t)rb * 768 + part * 256 + (kk + 1) * 32,
                          &Bbuf[(kk + 1) & 1][part * 4096 + rb * 32]);
                }
                #pragma unroll
                for (int n = 0; n < 4; ++n)
                    gld16(Asp + arow + (size_t)(n * 16) * 768 + (kk + 1) * 32,
                          &Abuf[(kk + 1) & 1][albase + n * 16 * 32]);
            }

            const unsigned short* A = Abuf[(kk + ph) & 1];
            const unsigned short* B = Bbuf[kk & 1];

            short8 af[4];
            #pragma unroll
            for (int i = 0; i < 4; ++i)
                af[i] = *(const short8*)&A[(m0w + i * 16 + col) * 32 + qp * 8];

            const int nparts = 3 - ph;            // A-h x {h,m,l}; A-m x {h,m}; A-l x {h}
            for (int bp = 0; bp < nparts; ++bp) {
                short8 bf[8];
                #pragma unroll
                for (int j = 0; j < 8; ++j)
                    bf[j] = *(const short8*)&B[bp * 4096 + (j * 16 + col) * 32 + qp * 8];
                #pragma unroll
                for (int i = 0; i < 4; ++i)
                    #pragma unroll
                    for (int j = 0; j < 8; ++j)
                        acc[i][j] = __builtin_amdgcn_mfma_f32_16x16x32_bf16(
                            af[i], bf[j], acc[i][j], 0, 0, 0);
            }
        }
    }

    // epilogue: dist = fl(fl(A - 2B) + C); argmin; C/D layout col=lane&15, row=quad*4+reg
    float cn[8]; int cidx[8];
    #pragma unroll
    for (int j = 0; j < 8; ++j) {
        cidx[j] = code0 + j * 16 + col;
        cn[j] = Cn[cidx[j]];
    }
    #pragma unroll
    for (int i = 0; i < 4; ++i) {
        #pragma unroll
        for (int r = 0; r < 4; ++r) {
            int token = token0 + m0w + i * 16 + quad * 4 + r;
            float Ai = An[token];
            float bv = FLT_INF; int bi = 0;
            #pragma unroll
            for (int j = 0; j < 8; ++j) {
                float d1 = fmaf(-2.f, acc[i][j][r], Ai);   // fl(A-2B): 2B exact
                float dist = d1 + cn[j];                    // fl(+C)
                if (dist < bv) { bv = dist; bi = cidx[j]; }
            }
            #pragma unroll
            for (int off = 8; off; off >>= 1) {
                float ov = __shfl_down(bv, off, 16);
                int   oi = __shfl_down(bi, off, 16);
                if (ov < bv || (ov == bv && oi < bi)) { bv = ov; bi = oi; }
            }
            if (col == 0) {
                unsigned long long key =
                    ((unsigned long long)__float_as_uint(bv) << 32) | (unsigned)bi;
                atomicMin(&keys[token], key);
            }
        }
    }
}

// ---------------- kernel 3: gather z_q + ST out + indices + loss partial ----------------
__global__ __launch_bounds__(256) void vq_gather(const float* __restrict__ z,
                                                 const float* __restrict__ cb,
                                                 const unsigned long long* __restrict__ keys,
                                                 float* __restrict__ out,
                                                 float* __restrict__ out_idx,
                                                 float* __restrict__ loss_acc) {
    int e4 = blockIdx.x * 256 + threadIdx.x;     // float4 index, 524288 total
    int t4 = e4 & 255;
    int rest = e4 >> 8;
    int d = rest & 255;
    int b = rest >> 8;
    int gbase = b * 1024 + t4 * 4;

    const int* klo = (const int*)keys;           // low word of each u64 key = index
    int i0 = klo[(size_t)(gbase + 0) * 2];
    int i1 = klo[(size_t)(gbase + 1) * 2];
    int i2 = klo[(size_t)(gbase + 2) * 2];
    int i3 = klo[(size_t)(gbase + 3) * 2];
    if (d == 0) {
        out_idx[gbase + 0] = (float)i0;
        out_idx[gbase + 1] = (float)i1;
        out_idx[gbase + 2] = (float)i2;
        out_idx[gbase + 3] = (float)i3;
    }

    float4 zv = *(const float4*)&z[(size_t)e4 * 4];
    float q0 = cb[(size_t)i0 * DD + d];
    float q1 = cb[(size_t)i1 * DD + d];
    float q2 = cb[(size_t)i2 * DD + d];
    float q3 = cb[(size_t)i3 * DD + d];

    float d0 = q0 - zv.x, d1 = q1 - zv.y, d2 = q2 - zv.z, d3 = q3 - zv.w;
    float4 o;                                    // replicate z + (z_q - z) rounding
    o.x = zv.x + d0; o.y = zv.y + d1; o.z = zv.z + d2; o.w = zv.w + d3;
    *(float4*)&out[(size_t)e4 * 4] = o;

    float s = d0 * d0 + d1 * d1 + d2 * d2 + d3 * d3;
    #pragma unroll
    for (int off = 32; off; off >>= 1) s += __shfl_down(s, off, 64);
    __shared__ float wsum[4];
    if ((threadIdx.x & 63) == 0) wsum[threadIdx.x >> 6] = s;
    __syncthreads();
    if (threadIdx.x == 0)
        atomicAdd(loss_acc, wsum[0] + wsum[1] + wsum[2] + wsum[3]);
}

// ---------------- kernel 4: finalize loss ----------------
__global__ void vq_loss(const float* __restrict__ loss_acc, float* __restrict__ out_loss) {
    *out_loss = 1.25f * (*loss_acc) / 2097152.f;
}

extern "C" void kernel_launch(void* const* d_in, const int* in_sizes, int n_in,
                              void* d_out, int out_size, void* d_ws, size_t ws_size,
                              hipStream_t stream) {
    const float* z  = (const float*)d_in[0];
    const float* cb = (const float*)d_in[1];
    float* out = (float*)d_out;
    char*  w   = (char*)d_ws;

    unsigned short* Asp = (unsigned short*)(w + ASP_B);
    unsigned short* Bsp = (unsigned short*)(w + BSP_B);
    float* An = (float*)(w + AN_B);
    float* Cn = (float*)(w + CN_B);
    unsigned long long* keys = (unsigned long long*)(w + KEY_B);
    float* lacc = (float*)(w + ACC_B);

    vq_prep   <<<32 + 2048 + 128, 256, 0, stream>>>(z, cb, An, Asp, Bsp, Cn, keys, lacc);
    vq_scores <<<2048, 256, 0, stream>>>(Asp, Bsp, An, Cn, keys);
    vq_gather <<<ZQ_SIZE / 1024, 256, 0, stream>>>(z, cb, keys, out, out + ZQ_SIZE, lacc);
    vq_loss   <<<1, 1, 0, stream>>>(lacc, out + ZQ_SIZE + BT);
}

// Round 9
// 269.224 us; speedup vs baseline: 1.3317x; 1.1089x over previous
//
#include <hip/hip_runtime.h>

#define DD   256
#define TT   1024
#define BT   8192
#define KK   8192
#define ZQ_SIZE 2097152

#define FLT_INF 3.402823466e38f

typedef __attribute__((ext_vector_type(8))) short short8;
typedef __attribute__((ext_vector_type(4))) float f32x4;

// ws layout (bytes)
// A2/B2: fragment-stream packing. 1024-B block per (16-row group, part, 32-k chunk):
//   short at blockbase + lane*8 + j holds X[row = grp*16 + (lane&15)][k = kk*32 + (lane>>4)*8 + j]
// A2[g 0..511][p 0..2][kk 0..7] ; B2[ng 0..511][p][kk]
#define A2_B    0u           // 512*3*8*1024 = 12582912 B
#define B2_B    12582912u
#define AN_B    25165824u    // An: 8192 f32
#define CN_B    25198592u    // Cn: 8192 f32
#define KEY_B   25231360u    // keys: 8192 u64
#define ACC_B   25296896u    // loss acc: 1 f32

static __device__ __forceinline__ unsigned short f2bf(float x) {  // RNE fp32->bf16
    unsigned int u = __float_as_uint(x);
    return (unsigned short)((u + 0x7FFF + ((u >> 16) & 1)) >> 16);
}
static __device__ __forceinline__ float bf2f(unsigned short h) {
    return __uint_as_float(((unsigned int)h) << 16);
}
// exact 3-term split: x == h + m + l (each difference exact in fp32)
static __device__ __forceinline__ void split3(float x, unsigned short& h,
                                              unsigned short& m, unsigned short& l) {
    h = f2bf(x);
    float r1 = x - bf2f(h);
    m = f2bf(r1);
    l = f2bf(r1 - bf2f(m));
}

static __device__ __forceinline__ void gld16(const void* g, const void* l) {
    __builtin_amdgcn_global_load_lds(
        (const __attribute__((address_space(1))) unsigned int*)g,
        (__attribute__((address_space(3))) unsigned int*)l, 16, 0, 0);
}

// ---------------- kernel 1: fused prep ----------------
// blocks 0..31:      An (token norms) + keys init + lacc init
// blocks 32..2079:   B2 frag-pack + Cn
// blocks 2080..2207: A2 frag-pack (via LDS transpose)
__global__ __launch_bounds__(256) void vq_prep(const float* __restrict__ z,
                                               const float* __restrict__ cb,
                                               float* __restrict__ An,
                                               unsigned short* __restrict__ A2,
                                               unsigned short* __restrict__ B2,
                                               float* __restrict__ Cn,
                                               unsigned long long* __restrict__ keys,
                                               float* __restrict__ lacc) {
    __shared__ float T[64][257];
    int tid = threadIdx.x;
    if (blockIdx.x < 32) {
        int g = blockIdx.x * 256 + tid;              // 0..8191 token
        int b = g >> 10, t = g & 1023;
        const float* zp = z + (size_t)b * (DD * TT) + t;
        float s = 0.f;
        #pragma unroll 8
        for (int d = 0; d < DD; ++d) {
            float v = zp[d * TT];
            float v2 = v * v;
            s = s + v2;
        }
        An[g] = s;
        keys[g] = ~0ull;
        if (g == 0) *lacc = 0.f;
    } else if (blockIdx.x < 32 + 2048) {
        // B2: cb -> fragment-stream packing ; Cn fused
        int g = (blockIdx.x - 32) * 256 + tid;       // 0..524287
        int code = g >> 6, d4 = (g & 63) * 4;
        float4 v = *(const float4*)&cb[(size_t)code * DD + d4];
        unsigned short h[4], m[4], l[4];
        split3(v.x, h[0], m[0], l[0]);
        split3(v.y, h[1], m[1], l[1]);
        split3(v.z, h[2], m[2], l[2]);
        split3(v.w, h[3], m[3], l[3]);
        int ng = code >> 4;
        int lane = ((d4 >> 3) & 3) * 16 + (code & 15);
        int kk = d4 >> 5;
        int jb = d4 & 7;                             // 0 or 4
        size_t base = (size_t)((ng * 3) * 8 + kk) * 512 + lane * 8 + jb;
        *(ushort4*)&B2[base]        = make_ushort4(h[0], h[1], h[2], h[3]);
        *(ushort4*)&B2[base + 4096] = make_ushort4(m[0], m[1], m[2], m[3]);
        *(ushort4*)&B2[base + 8192] = make_ushort4(l[0], l[1], l[2], l[3]);
        float s = v.x * v.x + v.y * v.y + v.z * v.z + v.w * v.w;
        #pragma unroll
        for (int off = 32; off; off >>= 1) s += __shfl_down(s, off, 64);
        if ((tid & 63) == 0) Cn[code] = s;
    } else {
        // A2 via LDS transpose: z[b,d,t] -> frag-stream packing
        int blk = blockIdx.x - 2080;                 // 0..127
        int b = blk >> 4;
        int t0 = (blk & 15) * 64;
        #pragma unroll
        for (int it = 0; it < 16; ++it) {
            int d = it * 16 + (tid >> 4);
            int t4 = (tid & 15) * 4;
            float4 v = *(const float4*)&z[(size_t)b * (DD * TT) + (size_t)d * TT + t0 + t4];
            T[t4 + 0][d] = v.x; T[t4 + 1][d] = v.y; T[t4 + 2][d] = v.z; T[t4 + 3][d] = v.w;
        }
        __syncthreads();
        int r = tid >> 2, q = tid & 3;
        int t = b * 1024 + t0 + r;
        int gA = t >> 4, ml = t & 15;
        #pragma unroll
        for (int dd = 0; dd < 16; ++dd) {
            int d = dd * 16 + q * 4;
            unsigned short h[4], m[4], l[4];
            #pragma unroll
            for (int c = 0; c < 4; ++c) split3(T[r][d + c], h[c], m[c], l[c]);
            int kk = d >> 5, quad = (d >> 3) & 3, jb = d & 7;
            size_t base = (size_t)((gA * 3) * 8 + kk) * 512 + (quad * 16 + ml) * 8 + jb;
            *(ushort4*)&A2[base]        = make_ushort4(h[0], h[1], h[2], h[3]);
            *(ushort4*)&A2[base + 4096] = make_ushort4(m[0], m[1], m[2], m[3]);
            *(ushort4*)&A2[base + 8192] = make_ushort4(l[0], l[1], l[2], l[3]);
        }
    }
}

// ---------------- kernel 2: bf16x3 MFMA distance GEMM + fused argmin ----------------
// 256(M)x128(N) block tile, 4 waves of 64x128 stacked in M. 8 kk chunks of 32 k.
// B: staged per kk via gld16 into LDS fragment blocks, double-buffered (2x24 KB)
//    -> bf reads are LINEAR (base + lane*16): zero bank conflicts by construction.
// A: read directly global->VGPR as coalesced dwordx4 fragment loads (L1/L2-hit,
//    fine-grained vmcnt, interleaves with MFMA -- no barrier involvement).
// One barrier per kk (8 total). Products per kk: (hh)(mh)(lh)(hm)(mm)(hl).
__global__ __launch_bounds__(256, 2) void vq_scores(const unsigned short* __restrict__ A2,
                                                    const unsigned short* __restrict__ B2,
                                                    const float* __restrict__ An,
                                                    const float* __restrict__ Cn,
                                                    unsigned long long* __restrict__ keys) {
    __shared__ __attribute__((aligned(16))) unsigned short Bl[2][12288];   // 2 x 24 KB

    // 8x8 block-group swizzle over the 32(mt) x 64(nt) tile grid
    int bid = blockIdx.x;
    int g = bid >> 6, sl = bid & 63;
    int mt = (g >> 3) * 8 + (sl >> 3);    // 0..31
    int nt = (g & 7) * 8 + (sl & 7);      // 0..63
    const int token0 = mt * 256, code0 = nt * 128;

    const int wid = threadIdx.x >> 6, lane = threadIdx.x & 63;
    const int quad = lane >> 4, col = lane & 15;

    // staging: 24 x 1KB frag blocks per kk (8 n-groups x 3 parts); wave does 6
    int sidx[6]; size_t soff[6];
    #pragma unroll
    for (int n = 0; n < 6; ++n) {
        int idx = wid * 6 + n;            // 0..23
        int p = idx >> 3, ngl = idx & 7;
        sidx[n] = idx * 512;              // LDS short offset (HW adds lane*16 B)
        soff[n] = (size_t)(((nt * 8 + ngl) * 3 + p) * 8) * 512 + lane * 8;
    }

    f32x4 acc[4][8];
    #pragma unroll
    for (int i = 0; i < 4; ++i)
        #pragma unroll
        for (int j = 0; j < 8; ++j) acc[i][j] = (f32x4){0.f, 0.f, 0.f, 0.f};

    // prologue: stage kk=0 -> buf 0
    #pragma unroll
    for (int n = 0; n < 6; ++n)
        gld16(B2 + soff[n], &Bl[0][sidx[n]]);

    const int gm0 = (token0 >> 4) + wid * 4;
    const int PP[6] = {0, 1, 2, 0, 1, 0};     // A-part
    const int QQ[6] = {0, 0, 0, 1, 1, 2};     // B-part (p+q<=2: exact 6-term schedule)

    for (int kk = 0; kk < 8; ++kk) {
        __syncthreads();   // drains buf[kk&1] gld16 (issued a full kk ago); prev readers done
        if (kk < 7) {      // prefetch kk+1 into the other buffer
            #pragma unroll
            for (int n = 0; n < 6; ++n)
                gld16(B2 + soff[n] + (size_t)(kk + 1) * 512, &Bl[(kk + 1) & 1][sidx[n]]);
        }
        const unsigned short* B = Bl[kk & 1];
        short8 bf[8];
        #pragma unroll
        for (int t = 0; t < 6; ++t) {
            const int p = PP[t], q = QQ[t];
            if (t == 0 || q != QQ[t - 1]) {       // load B-part fragments (linear reads)
                #pragma unroll
                for (int j = 0; j < 8; ++j)
                    bf[j] = *(const short8*)&B[(q * 8 + j) * 512 + lane * 8];
            }
            short8 af[4];
            #pragma unroll
            for (int i = 0; i < 4; ++i)           // direct global frag loads (coalesced)
                af[i] = *(const short8*)&A2[(size_t)(((gm0 + i) * 3 + p) * 8 + kk) * 512
                                            + lane * 8];
            #pragma unroll
            for (int i = 0; i < 4; ++i)
                #pragma unroll
                for (int j = 0; j < 8; ++j)
                    acc[i][j] = __builtin_amdgcn_mfma_f32_16x16x32_bf16(
                        af[i], bf[j], acc[i][j], 0, 0, 0);
        }
    }

    // epilogue: dist = fl(fl(A - 2B) + C); argmin; C/D layout col=lane&15, row=quad*4+reg
    float cn[8]; int cidx[8];
    #pragma unroll
    for (int j = 0; j < 8; ++j) {
        cidx[j] = code0 + j * 16 + col;
        cn[j] = Cn[cidx[j]];
    }
    #pragma unroll
    for (int i = 0; i < 4; ++i) {
        #pragma unroll
        for (int r = 0; r < 4; ++r) {
            int token = token0 + wid * 64 + i * 16 + quad * 4 + r;
            float Ai = An[token];
            float bv = FLT_INF; int bi = 0;
            #pragma unroll
            for (int j = 0; j < 8; ++j) {
                float d1 = fmaf(-2.f, acc[i][j][r], Ai);   // fl(A-2B): 2B exact
                float dist = d1 + cn[j];                    // fl(+C)
                if (dist < bv) { bv = dist; bi = cidx[j]; }
            }
            #pragma unroll
            for (int off = 8; off; off >>= 1) {
                float ov = __shfl_down(bv, off, 16);
                int   oi = __shfl_down(bi, off, 16);
                if (ov < bv || (ov == bv && oi < bi)) { bv = ov; bi = oi; }
            }
            if (col == 0) {
                unsigned long long key =
                    ((unsigned long long)__float_as_uint(bv) << 32) | (unsigned)bi;
                atomicMin(&keys[token], key);
            }
        }
    }
}

// ---------------- kernel 3: gather z_q + ST out + indices + loss partial ----------------
__global__ __launch_bounds__(256) void vq_gather(const float* __restrict__ z,
                                                 const float* __restrict__ cb,
                                                 const unsigned long long* __restrict__ keys,
                                                 float* __restrict__ out,
                                                 float* __restrict__ out_idx,
                                                 float* __restrict__ loss_acc) {
    int e4 = blockIdx.x * 256 + threadIdx.x;     // float4 index, 524288 total
    int t4 = e4 & 255;
    int rest = e4 >> 8;
    int d = rest & 255;
    int b = rest >> 8;
    int gbase = b * 1024 + t4 * 4;

    const int* klo = (const int*)keys;           // low word of each u64 key = index
    int i0 = klo[(size_t)(gbase + 0) * 2];
    int i1 = klo[(size_t)(gbase + 1) * 2];
    int i2 = klo[(size_t)(gbase + 2) * 2];
    int i3 = klo[(size_t)(gbase + 3) * 2];
    if (d == 0) {
        out_idx[gbase + 0] = (float)i0;
        out_idx[gbase + 1] = (float)i1;
        out_idx[gbase + 2] = (float)i2;
        out_idx[gbase + 3] = (float)i3;
    }

    float4 zv = *(const float4*)&z[(size_t)e4 * 4];
    float q0 = cb[(size_t)i0 * DD + d];
    float q1 = cb[(size_t)i1 * DD + d];
    float q2 = cb[(size_t)i2 * DD + d];
    float q3 = cb[(size_t)i3 * DD + d];

    float d0 = q0 - zv.x, d1 = q1 - zv.y, d2 = q2 - zv.z, d3 = q3 - zv.w;
    float4 o;                                    // replicate z + (z_q - z) rounding
    o.x = zv.x + d0; o.y = zv.y + d1; o.z = zv.z + d2; o.w = zv.w + d3;
    *(float4*)&out[(size_t)e4 * 4] = o;

    float s = d0 * d0 + d1 * d1 + d2 * d2 + d3 * d3;
    #pragma unroll
    for (int off = 32; off; off >>= 1) s += __shfl_down(s, off, 64);
    __shared__ float wsum[4];
    if ((threadIdx.x & 63) == 0) wsum[threadIdx.x >> 6] = s;
    __syncthreads();
    if (threadIdx.x == 0)
        atomicAdd(loss_acc, wsum[0] + wsum[1] + wsum[2] + wsum[3]);
}

// ---------------- kernel 4: finalize loss ----------------
__global__ void vq_loss(const float* __restrict__ loss_acc, float* __restrict__ out_loss) {
    *out_loss = 1.25f * (*loss_acc) / 2097152.f;
}

extern "C" void kernel_launch(void* const* d_in, const int* in_sizes, int n_in,
                              void* d_out, int out_size, void* d_ws, size_t ws_size,
                              hipStream_t stream) {
    const float* z  = (const float*)d_in[0];
    const float* cb = (const float*)d_in[1];
    float* out = (float*)d_out;
    char*  w   = (char*)d_ws;

    unsigned short* A2 = (unsigned short*)(w + A2_B);
    unsigned short* B2 = (unsigned short*)(w + B2_B);
    float* An = (float*)(w + AN_B);
    float* Cn = (float*)(w + CN_B);
    unsigned long long* keys = (unsigned long long*)(w + KEY_B);
    float* lacc = (float*)(w + ACC_B);

    vq_prep   <<<32 + 2048 + 128, 256, 0, stream>>>(z, cb, An, A2, B2, Cn, keys, lacc);
    vq_scores <<<2048, 256, 0, stream>>>(A2, B2, An, Cn, keys);
    vq_gather <<<ZQ_SIZE / 1024, 256, 0, stream>>>(z, cb, keys, out, out + ZQ_SIZE, lacc);
    vq_loss   <<<1, 1, 0, stream>>>(lacc, out + ZQ_SIZE + BT);
}